// Round 4
// baseline (26.264 us; speedup 1.0000x reference)
//
#include <hip/hip_runtime.h>
#include <cstdint>
#include <cstddef>

#define BATCH 4
#define NTOK  4096
#define CCH   256
#define IMH   512
#define IMW   512
#define PMAXV 124
#define NKEYS (PMAXV * PMAXV)   // 15376

#define MATCH_BLOCKS 16
#define EM_BLOCKS    1024        // each block: 256 threads x float4 = 4 KB of em
#define W4           (IMW / 4)   // 128 float4 per row

typedef float v4f __attribute__((ext_vector_type(4)));  // native vec for nontemporal

// ---------------------------------------------------------------------------
// Kernel A: blocks [0,16)  -> match (per-block LDS first-occurrence table)
//           blocks [16,..) -> em precompute (coalesced float4 stencil)
//
// match: pos_shuffled is an exact permutation of pos_org, so argmin(L1 dist)
// == first exact coordinate match. Table keyed by p0*124+p1, atomicMin keeps
// the first j. 4 blocks per batch, each answers a quarter of the queries.
//
// em: em[r][c] = sum_ch |im[r][c]-im[r-1][c]| (r>0) + |im[r+1][c]-im[r][c]|
//     (r<H-1) + |im[r][c]-im[r][c-1]| (c>0) + |im[r][c+1]-im[r][c]| (c<W-1).
// One thread per float4 of columns: 3 aligned float4 loads (C,U,D) + 2 scalar
// edge loads per channel; horizontal diffs inside the float4 come from regs.
// ---------------------------------------------------------------------------
__global__ __launch_bounds__(256) void match_em_k(const int2* __restrict__ ps,
                                                  const int2* __restrict__ po,
                                                  const float* __restrict__ im,
                                                  int* __restrict__ idx_out,
                                                  float4* __restrict__ em) {
    __shared__ int tbl[NKEYS];   // 61.5 KB (allocated for all blocks; em blocks ignore)
    const int tid = threadIdx.x;

    if (blockIdx.x < MATCH_BLOCKS) {
        const int b = blockIdx.x >> 2;
        const int q = blockIdx.x & 3;

        for (int k = tid; k < NKEYS; k += 256) tbl[k] = 0x7FFFFFFF;
        __syncthreads();

        const int2* psb = ps + (size_t)b * NTOK;
        for (int j = tid; j < NTOK; j += 256) {
            int2 p = psb[j];
            atomicMin(&tbl[p.x * PMAXV + p.y], j);
        }
        __syncthreads();

        const int2* pob = po + (size_t)b * NTOK;
        const int i0 = q * (NTOK / 4);
        for (int i = i0 + tid; i < i0 + NTOK / 4; i += 256) {
            int2 p = pob[i];
            idx_out[b * NTOK + i] = tbl[p.x * PMAXV + p.y];
        }
        return;
    }

    // ---- em tile ----
    const int t  = (blockIdx.x - MATCH_BLOCKS) * 256 + tid;  // over B*H*W4
    const int w4 = t % W4;
    const int h  = (t / W4) % IMH;
    const int b  = t / (W4 * IMH);

    float4 acc = make_float4(0.f, 0.f, 0.f, 0.f);
    const int col0 = w4 * 4;

#pragma unroll
    for (int ch = 0; ch < 3; ++ch) {
        const float* p = im + (((size_t)(b * 3 + ch)) * IMH + h) * IMW + col0;
        const float4 C = *(const float4*)p;
        if (h > 0) {
            const float4 U = *(const float4*)(p - IMW);
            acc.x += fabsf(C.x - U.x); acc.y += fabsf(C.y - U.y);
            acc.z += fabsf(C.z - U.z); acc.w += fabsf(C.w - U.w);
        }
        if (h < IMH - 1) {
            const float4 D = *(const float4*)(p + IMW);
            acc.x += fabsf(D.x - C.x); acc.y += fabsf(D.y - C.y);
            acc.z += fabsf(D.z - C.z); acc.w += fabsf(D.w - C.w);
        }
        // horizontal: internal diffs from registers, edges from scalar loads
        const float d01 = fabsf(C.y - C.x);
        const float d12 = fabsf(C.z - C.y);
        const float d23 = fabsf(C.w - C.z);
        acc.x += d01;        acc.y += d01 + d12;
        acc.z += d12 + d23;  acc.w += d23;
        if (col0 > 0)           acc.x += fabsf(C.x - p[-1]);
        if (col0 + 4 < IMW)     acc.w += fabsf(p[4] - C.w);
    }
    em[t] = acc;
}

// ---------------------------------------------------------------------------
// Kernel B: fused feat gather + dis from em.
// One 64-lane wave per (b,i) row:
//   - every lane copies one float4 of the C=256 feat row (1 KiB coalesced)
//   - lanes 0..3 each load one aligned float4 of em (one patch row: em rows
//     are y-indexed, cols x-indexed; patch = em[4*p.y + k][4*p.x .. +3])
//   - 2-step shfl reduce over lanes 0..3, lane 0 writes dis.
// ---------------------------------------------------------------------------
__global__ __launch_bounds__(256) void gather_dis_k(const float4* __restrict__ feat,
                                                    const float4* __restrict__ em,
                                                    const int2* __restrict__ po,
                                                    const int* __restrict__ idx_ws,
                                                    float4* __restrict__ out_feat,
                                                    float* __restrict__ out_dis) {
    const int tid  = threadIdx.x;
    const int lane = tid & 63;
    const int row  = blockIdx.x * 4 + (tid >> 6);   // flat (b,i), 0..16383
    const int b    = row >> 12;                     // row / NTOK

    // --- gather (all 64 lanes) ---
    const int idx = idx_ws[row];                    // wave-uniform: broadcast
    const float4 fv = feat[((size_t)(b * NTOK + idx)) * 64 + lane];
    v4f nv = { fv.x, fv.y, fv.z, fv.w };
    __builtin_nontemporal_store(nv, (v4f*)&out_feat[(size_t)row * 64 + lane]);

    // --- dis (lanes 0..3: one patch row each) ---
    float s = 0.f;
    if (lane < 4) {
        int2 p = po[row];
        const int r = p.y * 4 + lane;               // em row (y), col base = 4*p.x
        const float4 e = em[((size_t)b * IMH + r) * W4 + p.x];
        s = (e.x + e.y) + (e.z + e.w);
    }
    s += __shfl_xor(s, 1, 64);
    s += __shfl_xor(s, 2, 64);
    if (lane == 0) __builtin_nontemporal_store(s, &out_dis[row]);
}

extern "C" void kernel_launch(void* const* d_in, const int* in_sizes, int n_in,
                              void* d_out, int out_size, void* d_ws, size_t ws_size,
                              hipStream_t stream) {
    const float* feat         = (const float*)d_in[0];
    const float* images       = (const float*)d_in[1];
    const int*   pos_org      = (const int*)d_in[2];
    const int*   pos_shuffled = (const int*)d_in[3];

    float* out_feat = (float*)d_out;
    float* out_dis  = out_feat + (size_t)BATCH * NTOK * CCH;

    int*    idx_ws = (int*)d_ws;                                   // 64 KB
    float4* em_ws  = (float4*)((char*)d_ws + 65536);               // 4 MB

    match_em_k<<<MATCH_BLOCKS + EM_BLOCKS, 256, 0, stream>>>(
        (const int2*)pos_shuffled, (const int2*)pos_org, images, idx_ws, em_ws);

    gather_dis_k<<<BATCH * NTOK / 4, 256, 0, stream>>>(
        (const float4*)feat, (const float4*)em_ws, (const int2*)pos_org, idx_ws,
        (float4*)out_feat, out_dis);
}

// Round 5
// 26.031 us; speedup vs baseline: 1.0089x; 1.0089x over previous
//
#include <hip/hip_runtime.h>
#include <cstdint>
#include <cstddef>

#define BATCH 4
#define NTOK  4096
#define CCH   256
#define IMH   512
#define IMW   512

#define ROWS_PER_BLOCK 16     // 4 waves x 4 rows
#define NBLOCKS (BATCH * NTOK / ROWS_PER_BLOCK)   // 1024

typedef float v4f __attribute__((ext_vector_type(4)));

// ---------------------------------------------------------------------------
// Single fused kernel. Block = 256 threads = 4 waves, owns 16 (b,i) rows.
//
// Phase 1 (match): pos_shuffled is an exact permutation of pos_org, so
// argmin(L1 dist) == first exact coordinate match (min j). Pack each pos as
// (x<<16)|y; 256 threads sweep the batch's 4096 entries (8 int4 loads each,
// 2 packed entries per int4), compare against the block's 16 query keys held
// in registers, atomicMin the match index into LDS (hits are rare).
//
// Phase 2 (gather+dis): wave w handles rows 4w..4w+3 sequentially:
//   - 64 lanes copy the C=256 feat row as float4 (1 KiB, coalesced),
//     nontemporal store (streaming output, don't evict feat/pos/images).
//   - lanes 0..47 recompute the em stencil for one (channel, patch-pixel):
//     em[r,c] = sum_ch |v-up|+|down-v|+|v-left|+|right-v| (border-clipped;
//     max patch coord 123*4+3=495<511 so only top/left guards can fire).
//   - full-wave shfl_xor reduce (lanes 48..63 contribute 0), lane 0 writes.
// ---------------------------------------------------------------------------
__global__ __launch_bounds__(256) void fused_k(const float4* __restrict__ feat,
                                               const float* __restrict__ im,
                                               const int2* __restrict__ po,
                                               const int4* __restrict__ ps4,
                                               float4* __restrict__ out_feat,
                                               float* __restrict__ out_dis) {
    __shared__ int s_key[ROWS_PER_BLOCK];
    __shared__ int s_idx[ROWS_PER_BLOCK];

    const int tid = threadIdx.x;
    const int r0  = blockIdx.x * ROWS_PER_BLOCK;    // first flat row (b,i)
    const int b   = r0 >> 12;                       // 256 blocks per batch

    if (tid < ROWS_PER_BLOCK) {
        int2 p = po[r0 + tid];
        s_key[tid] = (p.x << 16) | p.y;
        s_idx[tid] = 0x7FFFFFFF;
    }
    __syncthreads();

    // --- phase 1: scan (keys in registers) ---
    int kreg[ROWS_PER_BLOCK];
#pragma unroll
    for (int k = 0; k < ROWS_PER_BLOCK; ++k) kreg[k] = s_key[k];

    const int4* psb = ps4 + (size_t)b * (NTOK / 2);   // 2048 int4 per batch
#pragma unroll
    for (int it = 0; it < NTOK / 2 / 256; ++it) {     // 8 iterations
        const int u = it * 256 + tid;
        const int4 v = psb[u];
        const int e0 = (v.x << 16) | v.y;
        const int e1 = (v.z << 16) | v.w;
        const int j0 = 2 * u;
#pragma unroll
        for (int k = 0; k < ROWS_PER_BLOCK; ++k) {
            if (e0 == kreg[k]) atomicMin(&s_idx[k], j0);
            if (e1 == kreg[k]) atomicMin(&s_idx[k], j0 + 1);
        }
    }
    __syncthreads();

    // --- phase 2: gather + dis, 4 rows per wave ---
    const int lane = tid & 63;
    const int w    = tid >> 6;

#pragma unroll
    for (int q = 0; q < 4; ++q) {
        const int li  = w * 4 + q;          // local row 0..15
        const int row = r0 + li;            // flat (b,i)
        const int idx = s_idx[li];          // wave-uniform LDS broadcast
        const int key = s_key[li];

        // gather: one float4 per lane
        const float4 fv = feat[((size_t)(b * NTOK + idx)) * 64 + lane];
        v4f nv = { fv.x, fv.y, fv.z, fv.w };
        __builtin_nontemporal_store(nv, (v4f*)&out_feat[(size_t)row * 64 + lane]);

        // dis: lanes 0..47, ch = lane>>4, pixel = lane&15
        float s = 0.f;
        if (lane < 48) {
            const int px  = key >> 16;
            const int py  = key & 0xFFFF;
            const int ch  = lane >> 4;
            const int k   = lane & 15;
            const int col = px * 4 + (k >> 2);   // x indexes columns
            const int r   = py * 4 + (k & 3);    // y indexes rows
            const float* base = im + (((size_t)(b * 3 + ch)) * IMH + r) * IMW + col;
            const float v = base[0];
            if (r > 0)         s += fabsf(v - base[-IMW]);
            if (r < IMH - 1)   s += fabsf(base[IMW] - v);
            if (col > 0)       s += fabsf(v - base[-1]);
            if (col < IMW - 1) s += fabsf(base[1] - v);
        }
        s += __shfl_xor(s, 1,  64);
        s += __shfl_xor(s, 2,  64);
        s += __shfl_xor(s, 4,  64);
        s += __shfl_xor(s, 8,  64);
        s += __shfl_xor(s, 16, 64);
        s += __shfl_xor(s, 32, 64);
        if (lane == 0) __builtin_nontemporal_store(s, &out_dis[row]);
    }
}

extern "C" void kernel_launch(void* const* d_in, const int* in_sizes, int n_in,
                              void* d_out, int out_size, void* d_ws, size_t ws_size,
                              hipStream_t stream) {
    const float* feat         = (const float*)d_in[0];
    const float* images       = (const float*)d_in[1];
    const int*   pos_org      = (const int*)d_in[2];
    const int*   pos_shuffled = (const int*)d_in[3];

    float* out_feat = (float*)d_out;
    float* out_dis  = out_feat + (size_t)BATCH * NTOK * CCH;

    fused_k<<<NBLOCKS, 256, 0, stream>>>(
        (const float4*)feat, images, (const int2*)pos_org,
        (const int4*)pos_shuffled, (float4*)out_feat, out_dis);
}

// Round 6
// 25.259 us; speedup vs baseline: 1.0398x; 1.0306x over previous
//
#include <hip/hip_runtime.h>
#include <cstdint>
#include <cstddef>

#define BATCH 4
#define NTOK  4096
#define CCH   256
#define IMH   512
#define IMW   512

#define ROWS_PER_BLOCK 4      // 4 waves x 1 row each -> max TLP, shortest chains
#define NBLOCKS (BATCH * NTOK / ROWS_PER_BLOCK)   // 4096

typedef float v4f __attribute__((ext_vector_type(4)));

// ---------------------------------------------------------------------------
// Single fused kernel. Block = 256 threads = 4 waves, owns 4 (b,i) rows.
//
// Phase 1 (match): pos_shuffled is an exact permutation of pos_org, so
// argmin(L1 dist) == first exact coordinate match (min j). Pack each pos as
// (x<<16)|y; 256 threads sweep the batch's 4096 entries (8 int4 loads each,
// 2 packed entries per int4), compare against the block's 4 query keys in
// registers, atomicMin the match index into LDS (hits are rare). The scan is
// 64x redundant across blocks but pos_shuffled is 32 KB/batch -> L2-resident.
//
// Phase 2 (gather+dis): wave w handles row w (ONE row per wave):
//   - 64 lanes copy the C=256 feat row as float4 (1 KiB, coalesced);
//     nontemporal load+store: feat is read-once, out is write-once -> keep
//     images/pos resident in L2.
//   - lanes 0..47 recompute the em stencil for one (channel, patch-pixel):
//     em[r,c] = sum_ch |v-up|+|down-v|+|v-left|+|right-v| (border-clipped;
//     max patch coord 123*4+3=495<511 so only top/left guards can fire).
//   - full-wave shfl_xor reduce (lanes 48..63 contribute 0), lane 0 writes.
// ---------------------------------------------------------------------------
__global__ __launch_bounds__(256) void fused_k(const float4* __restrict__ feat,
                                               const float* __restrict__ im,
                                               const int2* __restrict__ po,
                                               const int4* __restrict__ ps4,
                                               float4* __restrict__ out_feat,
                                               float* __restrict__ out_dis) {
    __shared__ int s_key[ROWS_PER_BLOCK];
    __shared__ int s_idx[ROWS_PER_BLOCK];

    const int tid = threadIdx.x;
    const int r0  = blockIdx.x * ROWS_PER_BLOCK;    // first flat row (b,i)
    const int b   = r0 >> 12;                       // 1024 blocks per batch

    if (tid < ROWS_PER_BLOCK) {
        int2 p = po[r0 + tid];
        s_key[tid] = (p.x << 16) | p.y;
        s_idx[tid] = 0x7FFFFFFF;
    }
    __syncthreads();

    // --- phase 1: scan (keys in registers) ---
    int kreg[ROWS_PER_BLOCK];
#pragma unroll
    for (int k = 0; k < ROWS_PER_BLOCK; ++k) kreg[k] = s_key[k];

    const int4* psb = ps4 + (size_t)b * (NTOK / 2);   // 2048 int4 per batch
#pragma unroll
    for (int it = 0; it < NTOK / 2 / 256; ++it) {     // 8 iterations
        const int u = it * 256 + tid;
        const int4 v = psb[u];
        const int e0 = (v.x << 16) | v.y;
        const int e1 = (v.z << 16) | v.w;
        const int j0 = 2 * u;
#pragma unroll
        for (int k = 0; k < ROWS_PER_BLOCK; ++k) {
            if (e0 == kreg[k]) atomicMin(&s_idx[k], j0);
            if (e1 == kreg[k]) atomicMin(&s_idx[k], j0 + 1);
        }
    }
    __syncthreads();

    // --- phase 2: gather + dis, ONE row per wave ---
    const int lane = tid & 63;
    const int w    = tid >> 6;

    const int row = r0 + w;             // flat (b,i)
    const int idx = s_idx[w];           // wave-uniform LDS broadcast
    const int key = s_key[w];

    // gather: one float4 per lane, streaming (read-once / write-once)
    const v4f fv = __builtin_nontemporal_load(
        (const v4f*)&feat[((size_t)(b * NTOK + idx)) * 64 + lane]);
    __builtin_nontemporal_store(fv, (v4f*)&out_feat[(size_t)row * 64 + lane]);

    // dis: lanes 0..47, ch = lane>>4, pixel = lane&15
    float s = 0.f;
    if (lane < 48) {
        const int px  = key >> 16;
        const int py  = key & 0xFFFF;
        const int ch  = lane >> 4;
        const int k   = lane & 15;
        const int col = px * 4 + (k >> 2);   // x indexes columns
        const int r   = py * 4 + (k & 3);    // y indexes rows
        const float* base = im + (((size_t)(b * 3 + ch)) * IMH + r) * IMW + col;
        const float v = base[0];
        if (r > 0)         s += fabsf(v - base[-IMW]);
        if (r < IMH - 1)   s += fabsf(base[IMW] - v);
        if (col > 0)       s += fabsf(v - base[-1]);
        if (col < IMW - 1) s += fabsf(base[1] - v);
    }
    s += __shfl_xor(s, 1,  64);
    s += __shfl_xor(s, 2,  64);
    s += __shfl_xor(s, 4,  64);
    s += __shfl_xor(s, 8,  64);
    s += __shfl_xor(s, 16, 64);
    s += __shfl_xor(s, 32, 64);
    if (lane == 0) __builtin_nontemporal_store(s, &out_dis[row]);
}

extern "C" void kernel_launch(void* const* d_in, const int* in_sizes, int n_in,
                              void* d_out, int out_size, void* d_ws, size_t ws_size,
                              hipStream_t stream) {
    const float* feat         = (const float*)d_in[0];
    const float* images       = (const float*)d_in[1];
    const int*   pos_org      = (const int*)d_in[2];
    const int*   pos_shuffled = (const int*)d_in[3];

    float* out_feat = (float*)d_out;
    float* out_dis  = out_feat + (size_t)BATCH * NTOK * CCH;

    fused_k<<<NBLOCKS, 256, 0, stream>>>(
        (const float4*)feat, images, (const int2*)pos_org,
        (const int4*)pos_shuffled, (float4*)out_feat, out_dis);
}